// Round 8
// baseline (71.265 us; speedup 1.0000x reference)
//
#include <hip/hip_runtime.h>
#include <cmath>

#define T_LEN 8192
#define B_ROWS 128
#define ND 360          // MAX_DELAY - MIN_DELAY
#define MIN_DELAY_C 60
#define BLOCK 1024      // 16 waves -> 4 waves/SIMD
#define GA 1680         // A guard: max lag read from A (pass3: 4*420)
#define GB 3360         // B guard: max lag read from B (chain: 8*420)

// Lag-doubling: 1/(1+S) = (1-S)(1+S^2)(1+S^4) / (1-S^8),  S = a1 z^-dA + a2 z^-dB
// Round 8: consecutive-PAIR mapping (8B lane stride = free 2-way bank alias,
// m136): lagged reads merge to ds_read2_b32, centers/writes/global stores are
// b64 -> LDS instruction count and latency events halved vs strided b32.
// Guards trimmed per-buffer. lgkm-only barriers + fused stores kept from R7.

#define BAR() do {                                             \
    asm volatile("s_waitcnt lgkmcnt(0)" ::: "memory");         \
    __builtin_amdgcn_s_barrier();                              \
    asm volatile("" ::: "memory");                             \
} while (0)

// One FIR pass over this thread's 4 sample-pairs t = 2*tid + 2048*k (+0,+1).
// All lagged reads for all pairs issued before any FMA (ILP batch).
// cen[] holds the center terms in registers across passes.
// STORE: emit final y for t < W (chain identity chunk) as b64.
template<int NT, int GSRC, int GDST, bool STORE>
__device__ __forceinline__ void fir_pairs(const float* __restrict__ src,
                                          float* __restrict__ dst,
                                          float* __restrict__ cen,
                                          const float* __restrict__ c,
                                          const int* __restrict__ l,
                                          int tid, float* __restrict__ gout, int W)
{
    float r0[4][NT], r1[4][NT];
#pragma unroll
    for (int k = 0; k < 4; ++k) {
        const int t = 2 * tid + 2048 * k;
#pragma unroll
        for (int j = 0; j < NT; ++j) {
            const int s = GSRC + t - l[j];
            r0[k][j] = src[s];           // adjacent dwords ->
            r1[k][j] = src[s + 1];       //   one ds_read2_b32
        }
    }
#pragma unroll
    for (int k = 0; k < 4; ++k) {
        const int t = 2 * tid + 2048 * k;
        float a0 = cen[2 * k], a1 = cen[2 * k + 1];
#pragma unroll
        for (int j = 0; j < NT; ++j) { a0 += c[j] * r0[k][j]; a1 += c[j] * r1[k][j]; }
        cen[2 * k] = a0; cen[2 * k + 1] = a1;
        *(float2*)&dst[GDST + t] = make_float2(a0, a1);      // ds_write_b64
        if (STORE) { if (t < W) *(float2*)&gout[t] = make_float2(a0, a1); }
    }
}

__global__ __launch_bounds__(BLOCK) void ks_resonator_kernel(
    const float* __restrict__ excitation,     // (128,1,8192)
    const float* __restrict__ gumbel,         // (360,)
    const float* __restrict__ delay_param,    // (360,)
    const float* __restrict__ feedback_gain,  // (1,)
    const float* __restrict__ refl,           // (2,)
    float* __restrict__ out)                  // (128,1,8192)
{
    __shared__ __align__(16) float A[GA + T_LEN];   // 39.5 KB ping (+guard)
    __shared__ __align__(16) float B[GB + T_LEN];   // 46.2 KB pong (+guard)
    __shared__ float s_c1[2], s_c2[3], s_c4[5], s_c8[9];
    __shared__ int   s_l1[2], s_l2[3], s_l4[5], s_l8[9];
    __shared__ int   s_dmin;

    const int tid = threadIdx.x;
    const int row = blockIdx.x;

    if (tid < 960) {
        // ---- waves 0-14: zero guards + load excitation row (float4) ----
        float4 z4 = make_float4(0.f, 0.f, 0.f, 0.f);
        float4* ag = (float4*)A;
        float4* bg = (float4*)B;
        for (int i = tid; i < GA / 4; i += 960) ag[i] = z4;
        for (int i = tid; i < GB / 4; i += 960) bg[i] = z4;
        const float4* __restrict__ x4 = (const float4*)(excitation + (size_t)row * T_LEN);
        float4* ax = (float4*)(A + GA);
        for (int i = tid; i < T_LEN / 4; i += 960) ax[i] = x4[i];
    } else {
        // ---- wave 15: argmax over (delay_param + gumbel) via shfl butterfly ----
        const int lane = tid - 960;
        float v = -INFINITY; int idx = 0;
        for (int i = lane; i < ND; i += 64) {
            float w = delay_param[i] + gumbel[i];
            if (w > v) { v = w; idx = i; }     // strict >: first occurrence wins
        }
#pragma unroll
        for (int off = 32; off > 0; off >>= 1) {
            float v2 = __shfl_xor(v, off);
            int   i2 = __shfl_xor(idx, off);
            if (v2 > v || (v2 == v && i2 < idx)) { v = v2; idx = i2; }
        }
        if (lane == 0) {
            const int p = idx;
            // rc = tanh(reflection_coeffs); k = resonant_activation(rc, 0) = tanh(rc)
            float k1 = tanhf(tanhf(refl[0]));
            float k2 = tanhf(tanhf(refl[1]));
            float a1 = k1 * (1.0f - k2);
            float a2 = fminf(fmaxf(k2, -0.999f), 0.999f);
            float bound = 0.999f - fabsf(a2);
            a1 = fminf(fmaxf(a1, -bound), bound);
            float fg = feedback_gain[0];
            float g = powf(1.0f / (1.0f + expf(-fg)), 0.45f);
            a1 *= g; a2 *= g;
            const int p2 = (p + 1) % ND;           // jnp.roll(one_hot, 1)
            const int dA = MIN_DELAY_C + p + 1;    // coeff 60+p multiplies y[t-(61+p)]
            const int dB = MIN_DELAY_C + p2 + 1;

            float p1[9], q2[9];
            p1[0] = 1.0f; q2[0] = 1.0f;
            for (int i = 1; i < 9; ++i) { p1[i] = p1[i-1] * a1; q2[i] = q2[i-1] * a2; }
            const float C2[3] = {1.f, 2.f, 1.f};
            const float C4[5] = {1.f, 4.f, 6.f, 4.f, 1.f};
            const float C8[9] = {1.f, 8.f, 28.f, 56.f, 70.f, 56.f, 28.f, 8.f, 1.f};
            // (1 - S):
            s_c1[0] = -a1; s_l1[0] = dA;
            s_c1[1] = -a2; s_l1[1] = dB;
            // S^m = sum_i C(m,i) a1^i a2^(m-i) z^-(i*dA + (m-i)*dB)
            for (int i = 0; i < 3; ++i) { s_c2[i] = C2[i] * p1[i] * q2[2-i]; s_l2[i] = i*dA + (2-i)*dB; }
            for (int i = 0; i < 5; ++i) { s_c4[i] = C4[i] * p1[i] * q2[4-i]; s_l4[i] = i*dA + (4-i)*dB; }
            for (int i = 0; i < 9; ++i) { s_c8[i] = C8[i] * p1[i] * q2[8-i]; s_l8[i] = i*dA + (8-i)*dB; }
            s_dmin = (dA < dB) ? dA : dB;
        }
    }
    BAR();   // row + guards + tables ready

    float* __restrict__ o = out + (size_t)row * T_LEN;
    const int W = 8 * s_dmin;   // chain chunk width = min S^8 lag, 488..3360 (even)

    // ---- centers into registers (b64 pair reads, 2-way alias = free) ----
    float cen[8];
#pragma unroll
    for (int k = 0; k < 4; ++k) {
        float2 c2 = *(const float2*)&A[GA + 2 * tid + 2048 * k];
        cen[2 * k] = c2.x; cen[2 * k + 1] = c2.y;
    }

    // ---- pass 1: B = (1 - S) A ----
    {
        float c[2]; int l[2];
#pragma unroll
        for (int j = 0; j < 2; ++j) { c[j] = s_c1[j]; l[j] = s_l1[j]; }
        fir_pairs<2, GA, GB, false>(A, B, cen, c, l, tid, nullptr, 0);
    }
    BAR();

    // ---- pass 2: A = (1 + S^2) B ----
    {
        float c[3]; int l[3];
#pragma unroll
        for (int j = 0; j < 3; ++j) { c[j] = s_c2[j]; l[j] = s_l2[j]; }
        fir_pairs<3, GB, GA, false>(B, A, cen, c, l, tid, nullptr, 0);
    }
    BAR();

    // ---- pass 3: B = (1 + S^4) A; fused store of y[0..W) = w[0..W) ----
    {
        float c[5]; int l[5];
#pragma unroll
        for (int j = 0; j < 5; ++j) { c[j] = s_c4[j]; l[j] = s_l4[j]; }
        fir_pairs<5, GA, GB, true>(A, B, cen, c, l, tid, o, W);
    }
    BAR();

    // ---- chain: y = w + S^8 y in B (identity chunk skipped); pair-mapped ----
    {
        float c[9]; int l[9];
#pragma unroll
        for (int j = 0; j < 9; ++j) { c[j] = s_c8[j]; l[j] = s_l8[j]; }
        for (int pos = W; pos < T_LEN; pos += W) {
            int end = pos + W; if (end > T_LEN) end = T_LEN;
            for (int j = pos + 2 * tid; j < end; j += 2 * BLOCK) {
                const int base = GB + j;
                float r0[9], r1[9];
#pragma unroll
                for (int k = 0; k < 9; ++k) {          // ds_read2_b32 each
                    r0[k] = B[base - l[k]];
                    r1[k] = B[base - l[k] + 1];
                }
                const float2 w0 = *(const float2*)&B[base];
                // tree sums: short dependent-FMA path, both lanes of the pair
                float s0a = c[0]*r0[0] + c[1]*r0[1], s0b = c[2]*r0[2] + c[3]*r0[3];
                float s0c = c[4]*r0[4] + c[5]*r0[5], s0d = c[6]*r0[6] + c[7]*r0[7];
                float s0e = c[8]*r0[8] + w0.x;
                float y0  = (s0a + s0b) + (s0c + s0d) + s0e;
                float s1a = c[0]*r1[0] + c[1]*r1[1], s1b = c[2]*r1[2] + c[3]*r1[3];
                float s1c = c[4]*r1[4] + c[5]*r1[5], s1d = c[6]*r1[6] + c[7]*r1[7];
                float s1e = c[8]*r1[8] + w0.y;
                float y1  = (s1a + s1b) + (s1c + s1d) + s1e;
                *(float2*)&B[base] = make_float2(y0, y1);   // ds_write_b64
                *(float2*)&o[j]    = make_float2(y0, y1);   // fire-and-forget b64
            }
            BAR();                           // lgkm-only: stores stay in flight
        }
    }
}

extern "C" void kernel_launch(void* const* d_in, const int* in_sizes, int n_in,
                              void* d_out, int out_size, void* d_ws, size_t ws_size,
                              hipStream_t stream) {
    const float* excitation    = (const float*)d_in[0];
    const float* gumbel        = (const float*)d_in[1];
    const float* delay_param   = (const float*)d_in[2];
    const float* feedback_gain = (const float*)d_in[3];
    const float* refl          = (const float*)d_in[4];
    float* out = (float*)d_out;

    ks_resonator_kernel<<<B_ROWS, BLOCK, 0, stream>>>(
        excitation, gumbel, delay_param, feedback_gain, refl, out);
}

// Round 9
// 69.522 us; speedup vs baseline: 1.0251x; 1.0251x over previous
//
#include <hip/hip_runtime.h>
#include <cmath>

#define T_LEN 8192
#define B_ROWS 128
#define ND 360          // MAX_DELAY - MIN_DELAY
#define MIN_DELAY_C 60
#define BLOCK 1024      // 16 waves -> 4 waves/SIMD
#define NCH 8           // strided samples per thread: t = tid + k*BLOCK
#define GA 1680         // A guard: max lag read from A (pass3: 4*420)
#define GB 3360         // B guard: max lag read from B (chain: 8*420)

// Lag-doubling: 1/(1+S) = (1-S)(1+S^2)(1+S^4) / (1-S^8),  S = a1 z^-dA + a2 z^-dB
// Round 9 = R7 (best, 69.74us) + fast transcendentals on the serial coeff lane
// + A-guard trim + final-chunk peel (no dead B-write / trailing barrier).
// R8's pair mapping reverted (regressed: ds_read2 merges likely not emitted).

// lgkm-only barrier: LDS producer->consumer ordering without draining global
// stores (hipcc's __syncthreads inserts s_waitcnt vmcnt(0) = store-drain stall).
#define BAR() do {                                             \
    asm volatile("s_waitcnt lgkmcnt(0)" ::: "memory");         \
    __builtin_amdgcn_s_barrier();                              \
    asm volatile("" ::: "memory");                             \
} while (0)

// fast transcendentals (HW v_exp_f32/v_log_f32 paths; tol here is 1.6e-2)
__device__ __forceinline__ float ftanh(float x) {
    float e = __expf(2.0f * fminf(fmaxf(x, -15.0f), 15.0f));
    return (e - 1.0f) / (e + 1.0f);
}

// FIR quad over samples t = tid + (K0+u)*BLOCK, u=0..3, reading src at t-l[j]
// through the guard (no masking). Center term from cen[] registers.
// STORE: emit final y for t < W (y[0..W) == w[0..W), chain identity chunk).
template<int NT, int K0, int GSRC, int GDST, bool STORE>
__device__ __forceinline__ void fir_quad(const float* __restrict__ src,
                                         float* __restrict__ dst,
                                         float* __restrict__ cen,
                                         const float* __restrict__ c,
                                         const int* __restrict__ l,
                                         int tid, float* __restrict__ gout, int W)
{
    float r[4][NT];
#pragma unroll
    for (int u = 0; u < 4; ++u) {
        const int t = tid + (K0 + u) * BLOCK;
#pragma unroll
        for (int j = 0; j < NT; ++j) r[u][j] = src[GSRC + t - l[j]];
    }
#pragma unroll
    for (int u = 0; u < 4; ++u) {
        const int t = tid + (K0 + u) * BLOCK;
        float acc = cen[K0 + u];
#pragma unroll
        for (int j = 0; j < NT; ++j) acc += c[j] * r[u][j];
        cen[K0 + u] = acc;
        dst[GDST + t] = acc;
        if (STORE) { if (t < W) gout[t] = acc; }
    }
}

__global__ __launch_bounds__(BLOCK) void ks_resonator_kernel(
    const float* __restrict__ excitation,     // (128,1,8192)
    const float* __restrict__ gumbel,         // (360,)
    const float* __restrict__ delay_param,    // (360,)
    const float* __restrict__ feedback_gain,  // (1,)
    const float* __restrict__ refl,           // (2,)
    float* __restrict__ out)                  // (128,1,8192)
{
    __shared__ __align__(16) float A[GA + T_LEN];   // 39.5 KB ping (+guard)
    __shared__ __align__(16) float B[GB + T_LEN];   // 46.2 KB pong (+guard)
    __shared__ float s_c1[2], s_c2[3], s_c4[5], s_c8[9];
    __shared__ int   s_l1[2], s_l2[3], s_l4[5], s_l8[9];
    __shared__ int   s_dmin;

    const int tid = threadIdx.x;
    const int row = blockIdx.x;

    if (tid < 960) {
        // ---- waves 0-14: zero guards + load excitation row (float4) ----
        float4 z4 = make_float4(0.f, 0.f, 0.f, 0.f);
        float4* ag = (float4*)A;
        float4* bg = (float4*)B;
        for (int i = tid; i < GA / 4; i += 960) ag[i] = z4;
        for (int i = tid; i < GB / 4; i += 960) bg[i] = z4;
        const float4* __restrict__ x4 = (const float4*)(excitation + (size_t)row * T_LEN);
        float4* ax = (float4*)(A + GA);
        for (int i = tid; i < T_LEN / 4; i += 960) ax[i] = x4[i];
    } else {
        // ---- wave 15: argmax over (delay_param + gumbel) via shfl butterfly ----
        const int lane = tid - 960;
        float v = -INFINITY; int idx = 0;
        for (int i = lane; i < ND; i += 64) {
            float w = delay_param[i] + gumbel[i];
            if (w > v) { v = w; idx = i; }     // strict >: first occurrence wins
        }
#pragma unroll
        for (int off = 32; off > 0; off >>= 1) {
            float v2 = __shfl_xor(v, off);
            int   i2 = __shfl_xor(idx, off);
            if (v2 > v || (v2 == v && i2 < idx)) { v = v2; idx = i2; }
        }
        if (lane == 0) {
            const int p = idx;
            // rc = tanh(reflection_coeffs); k = resonant_activation(rc, 0) = tanh(rc)
            float k1 = ftanh(ftanh(refl[0]));
            float k2 = ftanh(ftanh(refl[1]));
            float a1 = k1 * (1.0f - k2);
            float a2 = fminf(fmaxf(k2, -0.999f), 0.999f);
            float bound = 0.999f - fabsf(a2);
            a1 = fminf(fmaxf(a1, -bound), bound);
            float fg = feedback_gain[0];
            float sig = 1.0f / (1.0f + __expf(-fg));
            float g = __expf(0.45f * __logf(sig));       // sig^0.45, sig in (0,1)
            a1 *= g; a2 *= g;
            const int p2 = (p + 1) % ND;           // jnp.roll(one_hot, 1)
            const int dA = MIN_DELAY_C + p + 1;    // coeff 60+p multiplies y[t-(61+p)]
            const int dB = MIN_DELAY_C + p2 + 1;

            float p1[9], q2[9];
            p1[0] = 1.0f; q2[0] = 1.0f;
            for (int i = 1; i < 9; ++i) { p1[i] = p1[i-1] * a1; q2[i] = q2[i-1] * a2; }
            const float C2[3] = {1.f, 2.f, 1.f};
            const float C4[5] = {1.f, 4.f, 6.f, 4.f, 1.f};
            const float C8[9] = {1.f, 8.f, 28.f, 56.f, 70.f, 56.f, 28.f, 8.f, 1.f};
            // (1 - S):
            s_c1[0] = -a1; s_l1[0] = dA;
            s_c1[1] = -a2; s_l1[1] = dB;
            // S^m = sum_i C(m,i) a1^i a2^(m-i) z^-(i*dA + (m-i)*dB)
            for (int i = 0; i < 3; ++i) { s_c2[i] = C2[i] * p1[i] * q2[2-i]; s_l2[i] = i*dA + (2-i)*dB; }
            for (int i = 0; i < 5; ++i) { s_c4[i] = C4[i] * p1[i] * q2[4-i]; s_l4[i] = i*dA + (4-i)*dB; }
            for (int i = 0; i < 9; ++i) { s_c8[i] = C8[i] * p1[i] * q2[8-i]; s_l8[i] = i*dA + (8-i)*dB; }
            s_dmin = (dA < dB) ? dA : dB;
        }
    }
    BAR();   // row + guards + tables ready

    float* __restrict__ o = out + (size_t)row * T_LEN;
    const int W = 8 * s_dmin;   // chain chunk width = min S^8 lag, 488..3360

    // ---- centers into registers (conflict-free strided b32) ----
    float cen[NCH];
#pragma unroll
    for (int k = 0; k < NCH; ++k) cen[k] = A[GA + tid + k * BLOCK];

    // ---- pass 1: B = (1 - S) A ----
    {
        float c[2]; int l[2];
#pragma unroll
        for (int j = 0; j < 2; ++j) { c[j] = s_c1[j]; l[j] = s_l1[j]; }
        fir_quad<2, 0, GA, GB, false>(A, B, cen, c, l, tid, nullptr, 0);
        fir_quad<2, 4, GA, GB, false>(A, B, cen, c, l, tid, nullptr, 0);
    }
    BAR();

    // ---- pass 2: A = (1 + S^2) B ----
    {
        float c[3]; int l[3];
#pragma unroll
        for (int j = 0; j < 3; ++j) { c[j] = s_c2[j]; l[j] = s_l2[j]; }
        fir_quad<3, 0, GB, GA, false>(B, A, cen, c, l, tid, nullptr, 0);
        fir_quad<3, 4, GB, GA, false>(B, A, cen, c, l, tid, nullptr, 0);
    }
    BAR();

    // ---- pass 3: B = (1 + S^4) A; fused store of y[0..W) = w[0..W) ----
    {
        float c[5]; int l[5];
#pragma unroll
        for (int j = 0; j < 5; ++j) { c[j] = s_c4[j]; l[j] = s_l4[j]; }
        fir_quad<5, 0, GA, GB, true>(A, B, cen, c, l, tid, o, W);
        fir_quad<5, 4, GA, GB, true>(A, B, cen, c, l, tid, o, W);
    }
    BAR();

    // ---- chain: y = w + S^8 y in B (identity chunk skipped); fused stores ----
    {
        float c[9]; int l[9];
#pragma unroll
        for (int j = 0; j < 9; ++j) { c[j] = s_c8[j]; l[j] = s_l8[j]; }
        for (int pos = W; pos < T_LEN; pos += W) {
            const int  end  = (pos + W > T_LEN) ? T_LEN : (pos + W);
            const bool last = (pos + W >= T_LEN);          // uniform
            for (int j = pos + tid; j < end; j += BLOCK) {   // <=4 iters, typ 1
                const int base = GB + j;
                float r[9];
#pragma unroll
                for (int k = 0; k < 9; ++k) r[k] = B[base - l[k]];  // unguarded
                const float w0 = B[base];
                // tree sum: short dependent-FMA path
                float t0 = c[0] * r[0] + c[1] * r[1];
                float t1 = c[2] * r[2] + c[3] * r[3];
                float t2 = c[4] * r[4] + c[5] * r[5];
                float t3 = c[6] * r[6] + c[7] * r[7];
                float t4 = c[8] * r[8] + w0;
                float y  = (t0 + t1) + (t2 + t3) + t4;
                if (!last) B[base] = y;      // nobody reads the final chunk
                o[j] = y;                    // fire-and-forget (no vmcnt drain)
            }
            if (!last) BAR();                // lgkm-only: stores stay in flight
        }
    }
}

extern "C" void kernel_launch(void* const* d_in, const int* in_sizes, int n_in,
                              void* d_out, int out_size, void* d_ws, size_t ws_size,
                              hipStream_t stream) {
    const float* excitation    = (const float*)d_in[0];
    const float* gumbel        = (const float*)d_in[1];
    const float* delay_param   = (const float*)d_in[2];
    const float* feedback_gain = (const float*)d_in[3];
    const float* refl          = (const float*)d_in[4];
    float* out = (float*)d_out;

    ks_resonator_kernel<<<B_ROWS, BLOCK, 0, stream>>>(
        excitation, gumbel, delay_param, feedback_gain, refl, out);
}